// Round 1
// baseline (682.238 us; speedup 1.0000x reference)
//
#include <hip/hip_runtime.h>

// Problem constants (from reference)
#define NNODES 100000
#define NFEAT  16
#define NEDGES 3200000
#define NLAYERS 4

// One edge is handled by 16 consecutive threads (one per feature).
// Gather h[src*16+f] across the 16 lanes is one contiguous 64B segment.
__global__ __launch_bounds__(256) void scatter_layer(
    const int*   __restrict__ src,
    const int*   __restrict__ dst,
    const float* __restrict__ wt,
    const float* __restrict__ lw,   // this layer's per-edge weights
    const float* __restrict__ h,    // input node features [NNODES, 16]
    float*       __restrict__ acc)  // accumulator [NNODES, 16] (pre-initialized)
{
    long t = (long)blockIdx.x * blockDim.x + threadIdx.x;
    int e = (int)(t >> 4);
    if (e >= NEDGES) return;
    int f = (int)(t & 15);

    int s = src[e];
    int d = dst[e];
    float w = wt[e] * lw[e];
    float v = w * h[s * NFEAT + f];
    atomicAdd(&acc[d * NFEAT + f], v);
}

__global__ __launch_bounds__(256) void sigmoid_inplace(float* __restrict__ out, int n)
{
    int i = blockIdx.x * blockDim.x + threadIdx.x;
    if (i < n) {
        float x = out[i];
        out[i] = 1.0f / (1.0f + expf(-2.0f * x));
    }
}

extern "C" void kernel_launch(void* const* d_in, const int* in_sizes, int n_in,
                              void* d_out, int out_size, void* d_ws, size_t ws_size,
                              hipStream_t stream)
{
    const float* h0  = (const float*)d_in[0];           // [NNODES,16]
    const int*   ei  = (const int*)d_in[1];             // [2, NEDGES] (int32: JAX x64 off)
    const float* wt  = (const float*)d_in[2];           // [NEDGES]
    const float* lw  = (const float*)d_in[3];           // [NLAYERS, NEDGES]

    const int* src = ei;
    const int* dst = ei + NEDGES;

    float* hw   = (float*)d_ws;       // 6.4 MB buffer in workspace
    float* hout = (float*)d_out;      // doubles as ping-pong buffer

    const size_t hbytes = (size_t)NNODES * NFEAT * sizeof(float);

    dim3 blk(256);
    dim3 grd((NEDGES * 16 + 255) / 256);

    // Layer 0: acc = h_0 + scatter(h_0)          -> hw
    hipMemcpyAsync(hw, h0, hbytes, hipMemcpyDeviceToDevice, stream);
    scatter_layer<<<grd, blk, 0, stream>>>(src, dst, wt, lw + 0 * NEDGES, h0, hw);

    // Layer 1: acc = h_0 + scatter(hw)           -> hout
    hipMemcpyAsync(hout, h0, hbytes, hipMemcpyDeviceToDevice, stream);
    scatter_layer<<<grd, blk, 0, stream>>>(src, dst, wt, lw + 1 * NEDGES, hw, hout);

    // Layer 2: acc = h_0 + scatter(hout)         -> hw
    hipMemcpyAsync(hw, h0, hbytes, hipMemcpyDeviceToDevice, stream);
    scatter_layer<<<grd, blk, 0, stream>>>(src, dst, wt, lw + 2 * NEDGES, hout, hw);

    // Layer 3: acc = scatter(hw)                 -> hout (zero-init, no residual)
    hipMemsetAsync(hout, 0, hbytes, stream);
    scatter_layer<<<grd, blk, 0, stream>>>(src, dst, wt, lw + 3 * NEDGES, hw, hout);

    // out = sigmoid(2*h)
    int n = NNODES * NFEAT;
    sigmoid_inplace<<<(n + 255) / 256, 256, 0, stream>>>(hout, n);
}